// Round 6
// baseline (337.530 us; speedup 1.0000x reference)
//
#include <hip/hip_runtime.h>

// HashEmbedding: out[t,:] = [ sum_h W[ht[word,h],:] * P[word,h]  (64 floats),
//                             P[ht[word,0],0], P[ht[word,1],1] ]
// TOKENS=819200, EMBED=64, H=2, out row = 66 floats (264 B).
//
// R5: MLP-doubling experiment. R4/R5 counters: FETCH=318MB == compulsory
// L2-miss traffic of random W-row gathers (419MB @ ~16% L2 hit), WRITE=238MB,
// 3.9 TB/s mixed vs fill's 6.1 TB/s; VALUBusy 6.6%; wave lifetime ~15us vs
// ~1us chain minimum -> queueing/latency-bound hypothesis. This version
// unrolls 8 tokens per 16-lane group (32 tokens/wave, 2x R2'), all access
// shapes identical: every W load / embed store stays a 128B-contiguous
// per-group f2 access. Level loads are issued in separate unrolled loops
// (all of level N before any consumer) to keep 32 independent W-row loads
// in flight per wave. VGPR ~100 (<=128 tier, >=4 waves/SIMD via
// __launch_bounds__(256,4)). Blocks halve to 6400.
// Falsifiable: if dur_us stays ~141, the ~4 TB/s mixed gather fabric rate is
// the ceiling -> pivot to locality or stop.

#define TOKENS (16384 * 50)
#define EMBED 64
#define OUT_STRIDE 66
#define UNROLL 8
#define TOK_PER_WAVE 32   // 4 groups * 8 tokens
#define TOK_PER_BLOCK 128 // 4 waves * 32

typedef float f2 __attribute__((ext_vector_type(2)));
typedef int   i2 __attribute__((ext_vector_type(2)));

__global__ __launch_bounds__(256, 4) void HashEmbedding_32401233281223_kernel(
    const int*   __restrict__ words, // [TOKENS]
    const int*   __restrict__ ht,    // [NUM_WORDS,2]
    const float* __restrict__ W,     // [NUM_BUCKETS,64]
    const float* __restrict__ P,     // [NUM_WORDS,2] (also indexed by bucket for pvals)
    float*       __restrict__ out)   // [TOKENS,66]
{
    const int tid  = blockIdx.x * 256 + threadIdx.x;
    const int wave = tid >> 6;
    const int lane = threadIdx.x & 63;
    const int grp  = lane >> 4;   // four 16-lane token-groups per wave
    const int gl   = lane & 15;   // lane within group

    // token for unroll step u: wave*32 + 4u + grp  -> at fixed u the four
    // groups hold 4 CONSECUTIVE tokens (adjacent 264B output rows); the
    // wave's 8 word-loads cover 32 consecutive ids (2 cache lines).
    const int tb = wave * TOK_PER_WAVE + grp;

    // ---- Level 0: word ids (broadcast within group) ----
    int w[UNROLL];
#pragma unroll
    for (int u = 0; u < UNROLL; ++u) w[u] = words[tb + 4 * u];

    // ---- Level 1: hash pairs + per-word P pairs (16 independent gathers) ----
    const i2* ht2 = (const i2*)ht;
    const f2* P2  = (const f2*)P;
    i2 h[UNROLL];
    f2 p[UNROLL];
#pragma unroll
    for (int u = 0; u < UNROLL; ++u) h[u] = ht2[w[u]];
#pragma unroll
    for (int u = 0; u < UNROLL; ++u) p[u] = P2[w[u]];

    // ---- Level 2: W rows. Per token 2 rows; lane gl covers floats
    // {2gl,2gl+1} (lo) and {32+2gl,32+2gl+1} (hi). 32 independent f2
    // gathers per thread-iteration set, each 128B-contiguous per group. ----
    const f2* W2 = (const f2*)W;  // row r = W2[r*32 + ...]
    f2 alo[UNROLL], ahi[UNROLL], blo[UNROLL], bhi[UNROLL];
#pragma unroll
    for (int u = 0; u < UNROLL; ++u) {
        const size_t ra = (size_t)h[u].x * 32;
        const size_t rb = (size_t)h[u].y * 32;
        alo[u] = W2[ra + gl];
        ahi[u] = W2[ra + 16 + gl];
        blo[u] = W2[rb + gl];
        bhi[u] = W2[rb + 16 + gl];
    }

    // ---- Compute + embed stores (temporal; 128B contiguous per group) ----
#pragma unroll
    for (int u = 0; u < UNROLL; ++u) {
        const f2 el = alo[u] * p[u].x + blo[u] * p[u].y;
        const f2 eh = ahi[u] * p[u].x + bhi[u] * p[u].y;
        float* o = out + (size_t)(tb + 4 * u) * OUT_STRIDE;
        *((f2*)o + gl)      = el;
        *((f2*)o + 16 + gl) = eh;
    }

    // ---- pvals: one lane per group gathers P by bucket id and stores ----
    if (gl == 0) {
#pragma unroll
        for (int u = 0; u < UNROLL; ++u) {
            const f2 q = { P[2 * h[u].x + 0], P[2 * h[u].y + 1] };
            float* o = out + (size_t)(tb + 4 * u) * OUT_STRIDE;
            *((f2*)(o + EMBED)) = q;
        }
    }
}

extern "C" void kernel_launch(void* const* d_in, const int* in_sizes, int n_in,
                              void* d_out, int out_size, void* d_ws, size_t ws_size,
                              hipStream_t stream) {
    const int*   words      = (const int*)d_in[0];
    const int*   hash_table = (const int*)d_in[1];
    const float* W          = (const float*)d_in[2];
    const float* P          = (const float*)d_in[3];
    float*       out        = (float*)d_out;

    const int blocks = TOKENS / TOK_PER_BLOCK;  // 6400
    HashEmbedding_32401233281223_kernel<<<blocks, 256, 0, stream>>>(
        words, hash_table, W, P, out);
}